// Round 1
// baseline (440.333 us; speedup 1.0000x reference)
//
#include <hip/hip_runtime.h>
#include <math.h>

// Problem constants
#define Bq 64
#define Nq 64
#define Mq 64
#define Cc 512
#define Hh 8
#define HD 64
#define FREQ 256

// ---------------------------------------------------------------------------
// emb[r, j] = cos(t[r]*freq[j]) (j<128) | sin(t[r]*freq[j-128]) (j>=128)
// freq[i] = exp(-ln(10000) * i / 128)
// r in [0, 4096), j in [0, 256)
__global__ void emb_kernel(const float* __restrict__ qpos, float* __restrict__ emb) {
    int idx = blockIdx.x * blockDim.x + threadIdx.x;   // 4096*256 total
    int r = idx >> 8;
    int j = idx & 255;
    float t = qpos[r];
    int i = j & 127;
    float freq = expf(-logf(10000.0f) * (float)i / 128.0f);
    float a = t * freq;
    emb[idx] = (j < 128) ? cosf(a) : sinf(a);
}

// ---------------------------------------------------------------------------
// Generic fp32 GEMM: C[M,N] = act(A[M,K] @ B[K,N] + bias) + residual
// BM=BN=64, BK=16, 256 threads, 4x4 microtile per thread.
// M % 64 == 0, N % 64 == 0, K % 16 == 0 assumed.
__global__ __launch_bounds__(256) void gemm_kernel(
        const float* __restrict__ A, const float* __restrict__ B,
        const float* __restrict__ bias, const float* __restrict__ residual,
        float* __restrict__ C, int M, int N, int K, int act) {
    __shared__ float As[16][64];
    __shared__ float Bs[16][64];
    const int tid = threadIdx.x;
    const int row0 = blockIdx.x * 64;
    const int col0 = blockIdx.y * 64;
    const int tr = tid >> 4;        // 0..15
    const int tc = tid & 15;        // 0..15
    const int arow = tid >> 2;      // 0..63
    const int ak   = (tid & 3) * 4; // 0,4,8,12
    const int bk   = tid >> 4;      // 0..15
    const int bc   = (tid & 15) * 4;// 0..60

    float acc[4][4] = {};

    for (int k0 = 0; k0 < K; k0 += 16) {
        float4 av = *(const float4*)(A + (size_t)(row0 + arow) * K + k0 + ak);
        As[ak + 0][arow] = av.x;
        As[ak + 1][arow] = av.y;
        As[ak + 2][arow] = av.z;
        As[ak + 3][arow] = av.w;
        float4 bv = *(const float4*)(B + (size_t)(k0 + bk) * N + col0 + bc);
        *(float4*)&Bs[bk][bc] = bv;
        __syncthreads();
#pragma unroll
        for (int kk = 0; kk < 16; ++kk) {
            float a[4], b[4];
#pragma unroll
            for (int i = 0; i < 4; ++i) a[i] = As[kk][tr * 4 + i];
#pragma unroll
            for (int j = 0; j < 4; ++j) b[j] = Bs[kk][tc * 4 + j];
#pragma unroll
            for (int i = 0; i < 4; ++i)
#pragma unroll
                for (int j = 0; j < 4; ++j)
                    acc[i][j] += a[i] * b[j];
        }
        __syncthreads();
    }

#pragma unroll
    for (int i = 0; i < 4; ++i) {
        int row = row0 + tr * 4 + i;
#pragma unroll
        for (int j = 0; j < 4; ++j) {
            int col = col0 + tc * 4 + j;
            float val = acc[i][j];
            if (bias) val += bias[col];
            if (act == 1) val = val * (1.0f / (1.0f + __expf(-val)));  // SiLU
            if (residual) val += residual[(size_t)row * N + col];
            C[(size_t)row * N + col] = val;
        }
    }
}

// ---------------------------------------------------------------------------
// Attention: one block (64 threads = 1 wave) per (n, h, b).
// scores[m] = scale * sum_d q[b,n,h,d] * pe[n,m,h,d] * k[b,m,h,d]
// softmax over m, then x[b,n,h,d] = sum_m attn[m] * v[b,m,h,d]
__global__ __launch_bounds__(64) void attn_kernel(
        const float* __restrict__ q, const float* __restrict__ k,
        const float* __restrict__ v, const float* __restrict__ pe,
        float* __restrict__ x) {
    const int n = blockIdx.x;
    const int h = blockIdx.y;
    const int b = blockIdx.z;
    const int t = threadIdx.x;  // 0..63

    __shared__ float qs[64];
    __shared__ float attn[64];

    qs[t] = q[((size_t)(b * Nq + n)) * Cc + h * HD + t];
    __syncthreads();

    // score for m = t
    const float* pe_row = pe + ((size_t)(n * Mq + t)) * Cc + h * HD;
    const float* k_row  = k  + ((size_t)(b * Mq + t)) * Cc + h * HD;
    float s = 0.0f;
#pragma unroll
    for (int d = 0; d < HD; ++d) s += qs[d] * pe_row[d] * k_row[d];
    s *= 0.125f;  // HD^-0.5

    // wave softmax across 64 lanes
    float mx = s;
#pragma unroll
    for (int off = 32; off > 0; off >>= 1) mx = fmaxf(mx, __shfl_xor(mx, off));
    float e = __expf(s - mx);
    float sum = e;
#pragma unroll
    for (int off = 32; off > 0; off >>= 1) sum += __shfl_xor(sum, off);
    attn[t] = e / sum;
    __syncthreads();

    // out for d = t
    float acc = 0.0f;
    const float* v_base = v + ((size_t)(b * Mq)) * Cc + h * HD + t;
#pragma unroll
    for (int m = 0; m < Mq; ++m) acc += attn[m] * v_base[(size_t)m * Cc];
    x[((size_t)(b * Nq + n)) * Cc + h * HD + t] = acc;
}

// ---------------------------------------------------------------------------
extern "C" void kernel_launch(void* const* d_in, const int* in_sizes, int n_in,
                              void* d_out, int out_size, void* d_ws, size_t ws_size,
                              hipStream_t stream) {
    const float* query = (const float*)d_in[0];   // [64,64,512]
    const float* qpos  = (const float*)d_in[1];   // [1,64,64]
    const float* Wq    = (const float*)d_in[2];
    const float* bqv   = (const float*)d_in[3];
    const float* Wk    = (const float*)d_in[4];
    const float* Wv    = (const float*)d_in[5];
    const float* bvv   = (const float*)d_in[6];
    const float* Wo    = (const float*)d_in[7];
    const float* bo    = (const float*)d_in[8];
    const float* W1    = (const float*)d_in[9];
    const float* b1    = (const float*)d_in[10];
    const float* W2    = (const float*)d_in[11];
    const float* b2    = (const float*)d_in[12];
    float* out = (float*)d_out;
    float* ws  = (float*)d_ws;

    const size_t NMC = (size_t)4096 * 512;  // 2,097,152 floats per buffer
    float* pe = ws;
    float* q  = ws + 1 * NMC;
    float* k  = ws + 2 * NMC;
    float* v  = ws + 3 * NMC;
    float* x  = ws + 4 * NMC;
    // reuse: emb (4096*256) lives in q's slot (dead before q written);
    //        hidden (4096*512) lives in k's slot (dead before k written)
    float* emb    = q;
    float* hidden = k;

    dim3 gemm_grid(64, 8);  // M/64 x N/64 (M=4096, N=512)

    // 1. featurize positions
    emb_kernel<<<4096, 256, 0, stream>>>(qpos, emb);
    // 2. hidden = silu(emb @ W1 + b1)   [4096,256]x[256,512]
    gemm_kernel<<<gemm_grid, 256, 0, stream>>>(emb, W1, b1, nullptr, hidden,
                                               4096, 512, 256, 1);
    // 3. pe = hidden @ W2 + b2          [4096,512]x[512,512]
    gemm_kernel<<<gemm_grid, 256, 0, stream>>>(hidden, W2, b2, nullptr, pe,
                                               4096, 512, 512, 0);
    // 4. q/k/v projections
    gemm_kernel<<<gemm_grid, 256, 0, stream>>>(query, Wq, bqv, nullptr, q,
                                               4096, 512, 512, 0);
    gemm_kernel<<<gemm_grid, 256, 0, stream>>>(query, Wk, nullptr, nullptr, k,
                                               4096, 512, 512, 0);
    gemm_kernel<<<gemm_grid, 256, 0, stream>>>(query, Wv, bvv, nullptr, v,
                                               4096, 512, 512, 0);
    // 5. attention
    dim3 attn_grid(Nq, Hh, Bq);
    attn_kernel<<<attn_grid, 64, 0, stream>>>(q, k, v, pe, x);
    // 6. out = x @ Wo + bo + query
    gemm_kernel<<<gemm_grid, 256, 0, stream>>>(x, Wo, bo, query, out,
                                               4096, 512, 512, 0);
}

// Round 2
// 203.058 us; speedup vs baseline: 2.1685x; 2.1685x over previous
//
#include <hip/hip_runtime.h>
#include <hip/hip_bf16.h>
#include <math.h>

typedef short short8 __attribute__((ext_vector_type(8)));
typedef float floatx4 __attribute__((ext_vector_type(4)));

__device__ __forceinline__ ushort f2bf(float f) {
    __hip_bfloat16 h = __float2bfloat16(f);
    return *reinterpret_cast<ushort*>(&h);
}
__device__ __forceinline__ void bf8_to_f32(uint4 u, float* f) {
    f[0] = __uint_as_float(u.x << 16); f[1] = __uint_as_float(u.x & 0xffff0000u);
    f[2] = __uint_as_float(u.y << 16); f[3] = __uint_as_float(u.y & 0xffff0000u);
    f[4] = __uint_as_float(u.z << 16); f[5] = __uint_as_float(u.z & 0xffff0000u);
    f[6] = __uint_as_float(u.w << 16); f[7] = __uint_as_float(u.w & 0xffff0000u);
}

// ---------------------------------------------------------------------------
// emb[r][j] (bf16): cos(t*freq) j<128 | sin(t*freq) j>=128; one block per r.
__global__ void emb_kernel(const float* __restrict__ qpos, ushort* __restrict__ emb) {
    int idx = blockIdx.x * 256 + threadIdx.x;
    int r = idx >> 8, j = idx & 255, i = j & 127;
    float t = qpos[r];
    float freq = __expf(-9.210340371976184f * (float)i * (1.0f / 128.0f));
    float a = t * freq;
    float v = (j < 128) ? __cosf(a) : __sinf(a);
    emb[idx] = f2bf(v);
}

// ---------------------------------------------------------------------------
// fp32 [R][C] -> bf16 transposed [C][R]
__global__ __launch_bounds__(256) void convT_kernel(const float* __restrict__ in,
        ushort* __restrict__ out, int R, int C) {
    __shared__ float t[32][33];
    int c0 = blockIdx.x * 32, r0 = blockIdx.y * 32;
    int tx = threadIdx.x, ty = threadIdx.y;
    for (int i = ty; i < 32; i += 8) t[i][tx] = in[(size_t)(r0 + i) * C + c0 + tx];
    __syncthreads();
    for (int i = ty; i < 32; i += 8) out[(size_t)(c0 + i) * R + r0 + tx] = f2bf(t[tx][i]);
}

// fp32 -> bf16 elementwise (float4 per thread)
__global__ void conv_bf16_kernel(const float* __restrict__ in, ushort* __restrict__ out) {
    int idx = blockIdx.x * 256 + threadIdx.x;
    float4 v = *(const float4*)(in + (size_t)idx * 4);
    ushort4 o;
    o.x = f2bf(v.x); o.y = f2bf(v.y); o.z = f2bf(v.z); o.w = f2bf(v.w);
    *(ushort4*)(out + (size_t)idx * 4) = o;
}

// ---------------------------------------------------------------------------
// bf16 MFMA GEMM: C[M,N] = act(A[M,K] @ B[K,N] + bias) (+ resid, fp32 out)
// A row-major [M][K] bf16, Bt row-major [N][K] bf16 (pre-transposed B).
// 64x64 tile, BK=32, 256 threads = 4 waves (2x2 of 32x32), MFMA 16x16x32.
__global__ __launch_bounds__(256) void gemm_bf16(
        const ushort* __restrict__ A, const ushort* __restrict__ Bt,
        const float* __restrict__ bias, const float* __restrict__ resid,
        void* __restrict__ Cout, int M, int N, int K, int act, int out_fp32) {
    __shared__ ushort As[64 * 40];   // rows padded to 40 bf16 (80 B, 16B-aligned)
    __shared__ ushort Bs[64 * 40];
    const int tid = threadIdx.x;
    const int lane = tid & 63;
    const int w = tid >> 6;
    const int wr = w >> 1, wc = w & 1;
    const int row0 = blockIdx.x * 64, col0 = blockIdx.y * 64;
    const int srow = tid >> 2, sch = tid & 3;
    const int l15 = lane & 15, quad = lane >> 4;

    floatx4 acc[2][2] = {};

    for (int k0 = 0; k0 < K; k0 += 32) {
        uint4 va = *(const uint4*)(A  + (size_t)(row0 + srow) * K + k0 + sch * 8);
        uint4 vb = *(const uint4*)(Bt + (size_t)(col0 + srow) * K + k0 + sch * 8);
        __syncthreads();
        *(uint4*)&As[srow * 40 + sch * 8] = va;
        *(uint4*)&Bs[srow * 40 + sch * 8] = vb;
        __syncthreads();
        short8 a0 = *(const short8*)&As[(wr * 32 + l15) * 40 + quad * 8];
        short8 a1 = *(const short8*)&As[(wr * 32 + 16 + l15) * 40 + quad * 8];
        short8 b0 = *(const short8*)&Bs[(wc * 32 + l15) * 40 + quad * 8];
        short8 b1 = *(const short8*)&Bs[(wc * 32 + 16 + l15) * 40 + quad * 8];
        acc[0][0] = __builtin_amdgcn_mfma_f32_16x16x32_bf16(a0, b0, acc[0][0], 0, 0, 0);
        acc[0][1] = __builtin_amdgcn_mfma_f32_16x16x32_bf16(a0, b1, acc[0][1], 0, 0, 0);
        acc[1][0] = __builtin_amdgcn_mfma_f32_16x16x32_bf16(a1, b0, acc[1][0], 0, 0, 0);
        acc[1][1] = __builtin_amdgcn_mfma_f32_16x16x32_bf16(a1, b1, acc[1][1], 0, 0, 0);
    }

#pragma unroll
    for (int i = 0; i < 2; ++i)
#pragma unroll
        for (int j = 0; j < 2; ++j) {
            int col = col0 + wc * 32 + j * 16 + l15;
            float bv = bias ? bias[col] : 0.0f;
#pragma unroll
            for (int r = 0; r < 4; ++r) {
                int row = row0 + wr * 32 + i * 16 + quad * 4 + r;
                float val = acc[i][j][r] + bv;
                if (act) val = val / (1.0f + __expf(-val));
                if (out_fp32) {
                    float rv = resid ? resid[(size_t)row * N + col] : 0.0f;
                    ((float*)Cout)[(size_t)row * N + col] = val + rv;
                } else {
                    ((ushort*)Cout)[(size_t)row * N + col] = f2bf(val);
                }
            }
        }
}

// ---------------------------------------------------------------------------
// Attention, bf16 in / bf16 out. Block = 256 thr per (h, b, n-half).
// k,v (64 m) + q (32 n) staged as fp32 in LDS; pe streamed from global.
// Lane map: lo = l&7 -> d-chunk lo*8, hi = l>>3 -> m = mg*8+hi.
__global__ __launch_bounds__(256) void attn_bf16(
        const ushort* __restrict__ qB, const ushort* __restrict__ kB,
        const ushort* __restrict__ vB, const ushort* __restrict__ peB,
        ushort* __restrict__ xB) {
    const int h = blockIdx.x, b = blockIdx.y, nh = blockIdx.z;
    const int tid = threadIdx.x;
    const int w = tid >> 6, l = tid & 63;
    const int lo = l & 7, hi = l >> 3;

    __shared__ float ks[64 * 64];
    __shared__ float vs[64 * 64];
    __shared__ float qs[32 * 64];

#pragma unroll
    for (int p = 0; p < 2; ++p) {
        int cid = p * 256 + tid;
        int row = cid >> 3, ch = cid & 7;
        uint4 ku = *(const uint4*)(kB + (size_t)(b * 64 + row) * 512 + h * 64 + ch * 8);
        uint4 vu = *(const uint4*)(vB + (size_t)(b * 64 + row) * 512 + h * 64 + ch * 8);
        float kf[8], vf[8];
        bf8_to_f32(ku, kf); bf8_to_f32(vu, vf);
#pragma unroll
        for (int j = 0; j < 8; ++j) {
            ks[row * 64 + ch * 8 + j] = kf[j];
            vs[row * 64 + ch * 8 + j] = vf[j];
        }
    }
    {
        int row = tid >> 3, ch = tid & 7;
        uint4 qu = *(const uint4*)(qB + (size_t)(b * 64 + nh * 32 + row) * 512 + h * 64 + ch * 8);
        float qf[8]; bf8_to_f32(qu, qf);
#pragma unroll
        for (int j = 0; j < 8; ++j) qs[row * 64 + ch * 8 + j] = qf[j];
    }
    __syncthreads();

    for (int i = 0; i < 8; ++i) {
        int nl = w + 4 * i;          // 0..31, wave-private n
        int n = nh * 32 + nl;
        float qf[8];
        *(float4*)&qf[0] = *(const float4*)&qs[nl * 64 + lo * 8];
        *(float4*)&qf[4] = *(const float4*)&qs[nl * 64 + lo * 8 + 4];

        float sreg[8];
#pragma unroll
        for (int mg = 0; mg < 8; ++mg) {
            int m = mg * 8 + hi;
            uint4 pu = *(const uint4*)(peB + (size_t)(n * 64 + m) * 512 + h * 64 + lo * 8);
            float pf[8]; bf8_to_f32(pu, pf);
            float kf[8];
            *(float4*)&kf[0] = *(const float4*)&ks[m * 64 + lo * 8];
            *(float4*)&kf[4] = *(const float4*)&ks[m * 64 + lo * 8 + 4];
            float p = 0.0f;
#pragma unroll
            for (int j = 0; j < 8; ++j) p = fmaf(qf[j] * kf[j], pf[j], p);
            p += __shfl_xor(p, 1);
            p += __shfl_xor(p, 2);
            p += __shfl_xor(p, 4);
            sreg[mg] = p * 0.125f;   // HD^-0.5
        }

        float mx = sreg[0];
#pragma unroll
        for (int mg = 1; mg < 8; ++mg) mx = fmaxf(mx, sreg[mg]);
        mx = fmaxf(mx, __shfl_xor(mx, 8));
        mx = fmaxf(mx, __shfl_xor(mx, 16));
        mx = fmaxf(mx, __shfl_xor(mx, 32));
        float sum = 0.0f;
#pragma unroll
        for (int mg = 0; mg < 8; ++mg) { sreg[mg] = __expf(sreg[mg] - mx); sum += sreg[mg]; }
        sum += __shfl_xor(sum, 8);
        sum += __shfl_xor(sum, 16);
        sum += __shfl_xor(sum, 32);
        float rs = 1.0f / sum;

        float acc[8] = {};
#pragma unroll
        for (int mg = 0; mg < 8; ++mg) {
            int m = mg * 8 + hi;
            float at = sreg[mg] * rs;
            float vf[8];
            *(float4*)&vf[0] = *(const float4*)&vs[m * 64 + lo * 8];
            *(float4*)&vf[4] = *(const float4*)&vs[m * 64 + lo * 8 + 4];
#pragma unroll
            for (int j = 0; j < 8; ++j) acc[j] = fmaf(at, vf[j], acc[j]);
        }
#pragma unroll
        for (int j = 0; j < 8; ++j) {
            acc[j] += __shfl_xor(acc[j], 8);
            acc[j] += __shfl_xor(acc[j], 16);
            acc[j] += __shfl_xor(acc[j], 32);
        }
        if (l < 8) {
            uint4 o;
            o.x = f2bf(acc[0]) | ((uint)f2bf(acc[1]) << 16);
            o.y = f2bf(acc[2]) | ((uint)f2bf(acc[3]) << 16);
            o.z = f2bf(acc[4]) | ((uint)f2bf(acc[5]) << 16);
            o.w = f2bf(acc[6]) | ((uint)f2bf(acc[7]) << 16);
            *(uint4*)(xB + (size_t)(b * 64 + n) * 512 + h * 64 + l * 8) = o;
        }
    }
}

// ---------------------------------------------------------------------------
extern "C" void kernel_launch(void* const* d_in, const int* in_sizes, int n_in,
                              void* d_out, int out_size, void* d_ws, size_t ws_size,
                              hipStream_t stream) {
    const float* query = (const float*)d_in[0];
    const float* qpos  = (const float*)d_in[1];
    const float* Wq    = (const float*)d_in[2];
    const float* bq    = (const float*)d_in[3];
    const float* Wk    = (const float*)d_in[4];
    const float* Wv    = (const float*)d_in[5];
    const float* bv    = (const float*)d_in[6];
    const float* Wo    = (const float*)d_in[7];
    const float* bo    = (const float*)d_in[8];
    const float* W1    = (const float*)d_in[9];
    const float* b1    = (const float*)d_in[10];
    const float* W2    = (const float*)d_in[11];
    const float* b2    = (const float*)d_in[12];
    float* out = (float*)d_out;
    char* ws = (char*)d_ws;

    ushort* embB    = (ushort*)(ws + 0);          // 4096x256 bf16 = 2 MB
    ushort* W1t     = (ushort*)(ws + 2097152);    // [512][256]
    ushort* W2t     = (ushort*)(ws + 2359296);    // [512][512]
    ushort* Wqt     = (ushort*)(ws + 2883584);
    ushort* Wkt     = (ushort*)(ws + 3407872);
    ushort* Wvt     = (ushort*)(ws + 3932160);
    ushort* Wot     = (ushort*)(ws + 4456448);
    ushort* queryB  = (ushort*)(ws + 4980736);    // 4096x512 bf16 = 4 MB each
    ushort* hiddenB = (ushort*)(ws + 9175040);
    ushort* peB     = (ushort*)(ws + 13369344);
    ushort* qBf     = (ushort*)(ws + 17563648);
    ushort* kBf     = (ushort*)(ws + 21757952);
    ushort* vBf     = (ushort*)(ws + 25952256);
    ushort* xB      = (ushort*)(ws + 30146560);   // end ~32.75 MB

    emb_kernel<<<4096, 256, 0, stream>>>(qpos, embB);
    dim3 tb(32, 8);
    convT_kernel<<<dim3(16, 8),  tb, 0, stream>>>(W1, W1t, 256, 512);
    convT_kernel<<<dim3(16, 16), tb, 0, stream>>>(W2, W2t, 512, 512);
    convT_kernel<<<dim3(16, 16), tb, 0, stream>>>(Wq, Wqt, 512, 512);
    convT_kernel<<<dim3(16, 16), tb, 0, stream>>>(Wk, Wkt, 512, 512);
    convT_kernel<<<dim3(16, 16), tb, 0, stream>>>(Wv, Wvt, 512, 512);
    convT_kernel<<<dim3(16, 16), tb, 0, stream>>>(Wo, Wot, 512, 512);
    conv_bf16_kernel<<<2048, 256, 0, stream>>>(query, queryB);

    dim3 gg(64, 8);  // M/64 x N/64
    gemm_bf16<<<gg, 256, 0, stream>>>(embB,    W1t, b1, nullptr, hiddenB, 4096, 512, 256, 1, 0);
    gemm_bf16<<<gg, 256, 0, stream>>>(hiddenB, W2t, b2, nullptr, peB,     4096, 512, 512, 0, 0);
    gemm_bf16<<<gg, 256, 0, stream>>>(queryB,  Wqt, bq, nullptr, qBf,     4096, 512, 512, 0, 0);
    gemm_bf16<<<gg, 256, 0, stream>>>(queryB,  Wkt, nullptr, nullptr, kBf, 4096, 512, 512, 0, 0);
    gemm_bf16<<<gg, 256, 0, stream>>>(queryB,  Wvt, bv, nullptr, vBf,     4096, 512, 512, 0, 0);

    attn_bf16<<<dim3(8, 64, 2), 256, 0, stream>>>(qBf, kBf, vBf, peB, xB);

    gemm_bf16<<<gg, 256, 0, stream>>>(xB, Wot, bo, query, out, 4096, 512, 512, 0, 1);
}

// Round 5
// 163.717 us; speedup vs baseline: 2.6896x; 1.2403x over previous
//
#include <hip/hip_runtime.h>
#include <hip/hip_bf16.h>
#include <math.h>

typedef short short8 __attribute__((ext_vector_type(8)));
typedef float floatx4 __attribute__((ext_vector_type(4)));

__device__ __forceinline__ ushort f2bf(float f) {
    __hip_bfloat16 h = __float2bfloat16(f);
    return *reinterpret_cast<ushort*>(&h);
}
__device__ __forceinline__ void bf8_to_f32(uint4 u, float* f) {
    f[0] = __uint_as_float(u.x << 16); f[1] = __uint_as_float(u.x & 0xffff0000u);
    f[2] = __uint_as_float(u.y << 16); f[3] = __uint_as_float(u.y & 0xffff0000u);
    f[4] = __uint_as_float(u.z << 16); f[5] = __uint_as_float(u.z & 0xffff0000u);
    f[6] = __uint_as_float(u.w << 16); f[7] = __uint_as_float(u.w & 0xffff0000u);
}

#define GLDS16(g, l) __builtin_amdgcn_global_load_lds( \
    (const __attribute__((address_space(1))) void*)(g), \
    (__attribute__((address_space(3))) void*)(l), 16, 0, 0)

// ---------------------------------------------------------------------------
// One batched prep kernel. grid (16,16,8), block (32,8).
// z 0..5: fp32 [R][512] -> bf16 transposed [512][R] (QKV packed into Wqkvt)
// z == 6: query fp32 -> bf16 (+ concat bias [bq | 0 | bv])
// z == 7: emb featurize: emb[r][j] = cos/sin(t[r]*freq[j&127]) as bf16
__global__ __launch_bounds__(256) void prep_kernel(
        const float* __restrict__ W1, const float* __restrict__ W2,
        const float* __restrict__ Wq, const float* __restrict__ Wk,
        const float* __restrict__ Wv, const float* __restrict__ Wo,
        const float* __restrict__ bq, const float* __restrict__ bv,
        const float* __restrict__ query, const float* __restrict__ qpos,
        ushort* __restrict__ W1t, ushort* __restrict__ W2t,
        ushort* __restrict__ Wqkvt, ushort* __restrict__ Wot,
        ushort* __restrict__ queryB, ushort* __restrict__ embB,
        float* __restrict__ biasC) {
    const int z = blockIdx.z;
    const int tx = threadIdx.x, ty = threadIdx.y;
    const int tid = ty * 32 + tx;
    if (z < 6) {
        const float* src; ushort* dst; int R;
        switch (z) {
            case 0:  src = W1; dst = W1t;              R = 256; break;
            case 1:  src = W2; dst = W2t;              R = 512; break;
            case 2:  src = Wq; dst = Wqkvt;            R = 512; break;
            case 3:  src = Wk; dst = Wqkvt + 512*512;  R = 512; break;
            case 4:  src = Wv; dst = Wqkvt + 1024*512; R = 512; break;
            default: src = Wo; dst = Wot;              R = 512; break;
        }
        const int r0 = blockIdx.y * 32, c0 = blockIdx.x * 32;
        if (r0 >= R) return;
        __shared__ float t[32][33];
        for (int i = ty; i < 32; i += 8) t[i][tx] = src[(size_t)(r0 + i) * 512 + c0 + tx];
        __syncthreads();
        for (int i = ty; i < 32; i += 8) dst[(size_t)(c0 + i) * R + r0 + tx] = f2bf(t[tx][i]);
    } else if (z == 6) {
        const int bid = blockIdx.y * 16 + blockIdx.x;
#pragma unroll
        for (int i = 0; i < 8; ++i) {
            size_t idx4 = (size_t)bid * 2048 + i * 256 + tid;  // 524288 float4 total
            float4 v = *(const float4*)(query + idx4 * 4);
            ushort4 o; o.x = f2bf(v.x); o.y = f2bf(v.y); o.z = f2bf(v.z); o.w = f2bf(v.w);
            *(ushort4*)(queryB + idx4 * 4) = o;
        }
        if (bid == 0) {
            for (int i = tid; i < 1536; i += 256)
                biasC[i] = (i < 512) ? bq[i] : ((i < 1024) ? 0.0f : bv[i - 1024]);
        }
    } else {
        const int bid = blockIdx.y * 16 + blockIdx.x;
        const int gt = bid * 256 + tid;     // 65536 threads x 16 elems = 1M
        const int e0 = gt * 16;
        const int r = e0 >> 8, j0 = e0 & 255;
        const float t = qpos[r];
        ushort o[16];
#pragma unroll
        for (int u = 0; u < 16; ++u) {
            int j = j0 + u, i = j & 127;
            float freq = __expf(-9.210340371976184f * (float)i * (1.0f / 128.0f));
            float a = t * freq;
            o[u] = f2bf((j < 128) ? __cosf(a) : __sinf(a));
        }
        *(uint4*)(embB + e0)     = *(uint4*)&o[0];
        *(uint4*)(embB + e0 + 8) = *(uint4*)&o[8];
    }
}

// ---------------------------------------------------------------------------
// bf16 MFMA GEMM with global_load_lds staging (m97-style, width=16).
// A [M][K] bf16, Bt [N][K] bf16. 64x64 tile, BK=32, 256 thr = 4 waves (2x2).
// LDS rows unpadded 64 B (2-way bank aliasing = free; required for lane x 16
// contiguous global_load_lds destination).
__global__ __launch_bounds__(256) void gemm_bf16(
        const ushort* __restrict__ A, const ushort* __restrict__ Bt,
        const float* __restrict__ bias, const float* __restrict__ resid,
        void* __restrict__ Cout, int M, int N, int K, int act, int out_fp32) {
    __shared__ ushort As[64 * 32];
    __shared__ ushort Bs[64 * 32];
    const int tid = threadIdx.x;
    const int l = tid & 63, w = tid >> 6;
    const int wr = w >> 1, wc = w & 1;
    const int row0 = blockIdx.x * 64, col0 = blockIdx.y * 64;
    const int l15 = l & 15, quad = l >> 4;
    const int arow = w * 16 + (l >> 2), koff = (l & 3) * 8;

    const ushort* gA = A  + (size_t)(row0 + arow) * K + koff;
    const ushort* gB = Bt + (size_t)(col0 + arow) * K + koff;
    ushort* lA = &As[w * 512 + l * 8];   // = wave base + lane*16 bytes
    ushort* lB = &Bs[w * 512 + l * 8];

    floatx4 acc[2][2] = {};

    for (int k0 = 0; k0 < K; k0 += 32) {
        __syncthreads();
        GLDS16(gA + k0, lA);
        GLDS16(gB + k0, lB);
        __syncthreads();
        short8 a0 = *(const short8*)&As[(wr * 32 + l15) * 32 + quad * 8];
        short8 a1 = *(const short8*)&As[(wr * 32 + 16 + l15) * 32 + quad * 8];
        short8 b0 = *(const short8*)&Bs[(wc * 32 + l15) * 32 + quad * 8];
        short8 b1 = *(const short8*)&Bs[(wc * 32 + 16 + l15) * 32 + quad * 8];
        acc[0][0] = __builtin_amdgcn_mfma_f32_16x16x32_bf16(a0, b0, acc[0][0], 0, 0, 0);
        acc[0][1] = __builtin_amdgcn_mfma_f32_16x16x32_bf16(a0, b1, acc[0][1], 0, 0, 0);
        acc[1][0] = __builtin_amdgcn_mfma_f32_16x16x32_bf16(a1, b0, acc[1][0], 0, 0, 0);
        acc[1][1] = __builtin_amdgcn_mfma_f32_16x16x32_bf16(a1, b1, acc[1][1], 0, 0, 0);
    }

#pragma unroll
    for (int i = 0; i < 2; ++i)
#pragma unroll
        for (int j = 0; j < 2; ++j) {
            int col = col0 + wc * 32 + j * 16 + l15;
            float bvv = bias ? bias[col] : 0.0f;
#pragma unroll
            for (int r = 0; r < 4; ++r) {
                int row = row0 + wr * 32 + i * 16 + quad * 4 + r;
                float val = acc[i][j][r] + bvv;
                if (act) val = val / (1.0f + __expf(-val));
                if (out_fp32) {
                    float rv = resid ? resid[(size_t)row * N + col] : 0.0f;
                    ((float*)Cout)[(size_t)row * N + col] = val + rv;
                } else {
                    ((ushort*)Cout)[(size_t)row * N + col] = f2bf(val);
                }
            }
        }
}

// ---------------------------------------------------------------------------
// Attention over fused qkv [4096][1536] bf16. Block = 256 thr per (h,b,nhalf).
__global__ __launch_bounds__(256) void attn_bf16(
        const ushort* __restrict__ qkv, const ushort* __restrict__ peB,
        ushort* __restrict__ xB) {
    const int h = blockIdx.x, b = blockIdx.y, nh = blockIdx.z;
    const int tid = threadIdx.x;
    const int w = tid >> 6, l = tid & 63;
    const int lo = l & 7, hi = l >> 3;

    __shared__ float ks[64 * 64];
    __shared__ float vs[64 * 64];
    __shared__ float qs[32 * 64];

#pragma unroll
    for (int p = 0; p < 2; ++p) {
        int cid = p * 256 + tid;
        int row = cid >> 3, ch = cid & 7;
        const ushort* base = qkv + (size_t)(b * 64 + row) * 1536 + h * 64 + ch * 8;
        uint4 ku = *(const uint4*)(base + 512);
        uint4 vu = *(const uint4*)(base + 1024);
        float kf[8], vf[8];
        bf8_to_f32(ku, kf); bf8_to_f32(vu, vf);
#pragma unroll
        for (int j = 0; j < 8; ++j) {
            ks[row * 64 + ch * 8 + j] = kf[j];
            vs[row * 64 + ch * 8 + j] = vf[j];
        }
    }
    {
        int row = tid >> 3, ch = tid & 7;
        uint4 qu = *(const uint4*)(qkv + (size_t)(b * 64 + nh * 32 + row) * 1536 + h * 64 + ch * 8);
        float qf[8]; bf8_to_f32(qu, qf);
#pragma unroll
        for (int j = 0; j < 8; ++j) qs[row * 64 + ch * 8 + j] = qf[j];
    }
    __syncthreads();

    for (int i = 0; i < 8; ++i) {
        int nl = w + 4 * i;
        int n = nh * 32 + nl;
        float qf[8];
        *(float4*)&qf[0] = *(const float4*)&qs[nl * 64 + lo * 8];
        *(float4*)&qf[4] = *(const float4*)&qs[nl * 64 + lo * 8 + 4];

        float sreg[8];
#pragma unroll
        for (int mg = 0; mg < 8; ++mg) {
            int m = mg * 8 + hi;
            uint4 pu = *(const uint4*)(peB + (size_t)(n * 64 + m) * 512 + h * 64 + lo * 8);
            float pf[8]; bf8_to_f32(pu, pf);
            float kf[8];
            *(float4*)&kf[0] = *(const float4*)&ks[m * 64 + lo * 8];
            *(float4*)&kf[4] = *(const float4*)&ks[m * 64 + lo * 8 + 4];
            float p = 0.0f;
#pragma unroll
            for (int j = 0; j < 8; ++j) p = fmaf(qf[j] * kf[j], pf[j], p);
            p += __shfl_xor(p, 1);
            p += __shfl_xor(p, 2);
            p += __shfl_xor(p, 4);
            sreg[mg] = p * 0.125f;
        }

        float mx = sreg[0];
#pragma unroll
        for (int mg = 1; mg < 8; ++mg) mx = fmaxf(mx, sreg[mg]);
        mx = fmaxf(mx, __shfl_xor(mx, 8));
        mx = fmaxf(mx, __shfl_xor(mx, 16));
        mx = fmaxf(mx, __shfl_xor(mx, 32));
        float sum = 0.0f;
#pragma unroll
        for (int mg = 0; mg < 8; ++mg) { sreg[mg] = __expf(sreg[mg] - mx); sum += sreg[mg]; }
        sum += __shfl_xor(sum, 8);
        sum += __shfl_xor(sum, 16);
        sum += __shfl_xor(sum, 32);
        float rs = 1.0f / sum;

        float acc[8] = {};
#pragma unroll
        for (int mg = 0; mg < 8; ++mg) {
            int m = mg * 8 + hi;
            float at = sreg[mg] * rs;
            float vf[8];
            *(float4*)&vf[0] = *(const float4*)&vs[m * 64 + lo * 8];
            *(float4*)&vf[4] = *(const float4*)&vs[m * 64 + lo * 8 + 4];
#pragma unroll
            for (int j = 0; j < 8; ++j) acc[j] = fmaf(at, vf[j], acc[j]);
        }
#pragma unroll
        for (int j = 0; j < 8; ++j) {
            acc[j] += __shfl_xor(acc[j], 8);
            acc[j] += __shfl_xor(acc[j], 16);
            acc[j] += __shfl_xor(acc[j], 32);
        }
        if (l < 8) {
            uint4 o;
            o.x = f2bf(acc[0]) | ((uint)f2bf(acc[1]) << 16);
            o.y = f2bf(acc[2]) | ((uint)f2bf(acc[3]) << 16);
            o.z = f2bf(acc[4]) | ((uint)f2bf(acc[5]) << 16);
            o.w = f2bf(acc[6]) | ((uint)f2bf(acc[7]) << 16);
            *(uint4*)(xB + (size_t)(b * 64 + n) * 512 + h * 64 + l * 8) = o;
        }
    }
}

// ---------------------------------------------------------------------------
extern "C" void kernel_launch(void* const* d_in, const int* in_sizes, int n_in,
                              void* d_out, int out_size, void* d_ws, size_t ws_size,
                              hipStream_t stream) {
    const float* query = (const float*)d_in[0];
    const float* qpos  = (const float*)d_in[1];
    const float* Wq    = (const float*)d_in[2];
    const float* bq    = (const float*)d_in[3];
    const float* Wk    = (const float*)d_in[4];
    const float* Wv    = (const float*)d_in[5];
    const float* bv    = (const float*)d_in[6];
    const float* Wo    = (const float*)d_in[7];
    const float* bo    = (const float*)d_in[8];
    const float* W1    = (const float*)d_in[9];
    const float* b1    = (const float*)d_in[10];
    const float* W2    = (const float*)d_in[11];
    const float* b2    = (const float*)d_in[12];
    float* out = (float*)d_out;
    char* ws = (char*)d_ws;

    ushort* W1t    = (ushort*)(ws + 0);          // [512][256]  256 KB
    ushort* W2t    = (ushort*)(ws + 262144);     // [512][512]  512 KB
    ushort* Wqkvt  = (ushort*)(ws + 786432);     // [1536][512] 1.5 MB
    ushort* Wot    = (ushort*)(ws + 2359296);    // [512][512]  512 KB
    float*  biasC  = (float*) (ws + 2883584);    // [1536]
    ushort* embB   = (ushort*)(ws + 3145728);    // [4096][256] 2 MB
    ushort* queryB = (ushort*)(ws + 5242880);    // [4096][512] 4 MB
    ushort* hiddenB= (ushort*)(ws + 9437184);    // 4 MB
    ushort* peB    = (ushort*)(ws + 13631488);   // 4 MB
    ushort* qkvB   = (ushort*)(ws + 17825792);   // [4096][1536] 12 MB
    ushort* xB     = (ushort*)(ws + 30408704);   // 4 MB -> end 34.6 MB

    prep_kernel<<<dim3(16, 16, 8), dim3(32, 8), 0, stream>>>(
        W1, W2, Wq, Wk, Wv, Wo, bq, bv, query, qpos,
        W1t, W2t, Wqkvt, Wot, queryB, embB, biasC);

    gemm_bf16<<<dim3(64, 8),  256, 0, stream>>>(embB,    W1t,   b1,    nullptr, hiddenB, 4096,  512, 256, 1, 0);
    gemm_bf16<<<dim3(64, 8),  256, 0, stream>>>(hiddenB, W2t,   b2,    nullptr, peB,     4096,  512, 512, 0, 0);
    gemm_bf16<<<dim3(64, 24), 256, 0, stream>>>(queryB,  Wqkvt, biasC, nullptr, qkvB,    4096, 1536, 512, 0, 0);

    attn_bf16<<<dim3(8, 64, 2), 256, 0, stream>>>(qkvB, peB, xB);

    gemm_bf16<<<dim3(64, 8),  256, 0, stream>>>(xB, Wot, bo, query, out, 4096, 512, 512, 0, 1);
}